// Round 6
// baseline (299.058 us; speedup 1.0000x reference)
//
#include <hip/hip_runtime.h>
#include <hip/hip_bf16.h>
#include <math.h>

#define N_NODES 6144
#define NFEAT 512
#define NHID 256
#define NHEADS 4
#define DHEAD 64
#define NEMBED 128
#define LRELU_ALPHA 0.2f
#define MAXC 256          // CSR capacity/row; degree ~Binom(6144,1%): mean 61, max~100
#define ASTRIDE 20        // out_gemm As pad
#define ATS 132           // gemm AsT row stride (words): breaks 4-way store conflict,
                          // keeps (132*4*kk + 32*ty) 16B-aligned for ds_read_b128

// ---------------------------------------------------------------------------
// Kernel 1: grid (48, 132).
//  y<4 : Wh[h]=x.W[h], 128x64 tile, 8x4 micro-tile (0.75 B LDS per FLOP ->
//        VALU-bound, not LDS-bound), transposed A-tile for b128 reads,
//        fused s/t epilogue.
//  y>=4: ONE adjacency row per block -> compact CSR (6144 blocks, full HBM
//        parallelism; co-resident with GEMM so the 151 MB stream overlaps).
// ---------------------------------------------------------------------------
__global__ __launch_bounds__(256) void gemm_scan(const float* __restrict__ x,
                                                 const float* __restrict__ W,
                                                 const float* __restrict__ a_src,
                                                 const float* __restrict__ a_dst,
                                                 const int* __restrict__ adj,
                                                 float* __restrict__ Wh,
                                                 float* __restrict__ s_arr,
                                                 float* __restrict__ t_arr,
                                                 int* __restrict__ cnt_g,
                                                 unsigned short* __restrict__ nbr_g) {
    __shared__ union SM {
        struct { float AsT[16][ATS]; float Bs[16][64]; } g;   // 8448+4096 B
        struct { unsigned short nbr[MAXC]; int cnt; } s;
    } sm;
    const int tid = threadIdx.x;

    if (blockIdx.y < NHEADS) {
        // ---------------- GEMM path: 128 rows x 64 cols per block ----------------
        const int tx = tid & 15;        // col group: 4 cols
        const int ty = tid >> 4;        // row group: 8 rows (0..15)
        const int row0 = blockIdx.x * 128;
        const int h = blockIdx.y;
        const float* Bp = W + (size_t)h * NFEAT * DHEAD;

        float acc[8][4] = {};

        const int lr = tid >> 2;        // 0..63: A-load row within pass
        const int lk = (tid & 3) * 4;   // A-load k quad

        for (int k0 = 0; k0 < NFEAT; k0 += 16) {
            // load A tile transposed: AsT[kk][row], 128 rows x 16 k
#pragma unroll
            for (int pass = 0; pass < 2; ++pass) {
                const int r = lr + pass * 64;
                const float4 v = *(const float4*)(x + (size_t)(row0 + r) * NFEAT + k0 + lk);
                sm.g.AsT[lk + 0][r] = v.x;
                sm.g.AsT[lk + 1][r] = v.y;
                sm.g.AsT[lk + 2][r] = v.z;
                sm.g.AsT[lk + 3][r] = v.w;
            }
            // load B tile: 16 k x 64 cols
            {
                const int kk = tid >> 4, cq = tid & 15;
                const float4 v = *(const float4*)(Bp + (size_t)(k0 + kk) * DHEAD + cq * 4);
                *(float4*)&sm.g.Bs[kk][cq * 4] = v;
            }
            __syncthreads();
#pragma unroll
            for (int kk = 0; kk < 16; kk++) {
                const float4 a0 = *(const float4*)&sm.g.AsT[kk][ty * 8];
                const float4 a1 = *(const float4*)&sm.g.AsT[kk][ty * 8 + 4];
                const float4 b  = *(const float4*)&sm.g.Bs[kk][tx * 4];
                const float a[8] = {a0.x, a0.y, a0.z, a0.w, a1.x, a1.y, a1.z, a1.w};
                const float bb[4] = {b.x, b.y, b.z, b.w};
#pragma unroll
                for (int i = 0; i < 8; i++)
#pragma unroll
                    for (int j = 0; j < 4; j++) acc[i][j] += a[i] * bb[j];
            }
            __syncthreads();
        }
        // store Wh
#pragma unroll
        for (int i = 0; i < 8; i++) {
            const int row = row0 + ty * 8 + i;
            float4 v = make_float4(acc[i][0], acc[i][1], acc[i][2], acc[i][3]);
            *(float4*)(Wh + ((size_t)h * N_NODES + row) * DHEAD + tx * 4) = v;
        }
        // fused s/t epilogue: 16-lane xor reduce over tx
        float a4s[4], a4d[4];
#pragma unroll
        for (int j = 0; j < 4; j++) {
            a4s[j] = a_src[h * DHEAD + tx * 4 + j];
            a4d[j] = a_dst[h * DHEAD + tx * 4 + j];
        }
#pragma unroll
        for (int i = 0; i < 8; i++) {
            float ps = acc[i][0] * a4s[0] + acc[i][1] * a4s[1] +
                       acc[i][2] * a4s[2] + acc[i][3] * a4s[3];
            float pt = acc[i][0] * a4d[0] + acc[i][1] * a4d[1] +
                       acc[i][2] * a4d[2] + acc[i][3] * a4d[3];
#pragma unroll
            for (int off = 1; off < 16; off <<= 1) {
                ps += __shfl_xor(ps, off);
                pt += __shfl_xor(pt, off);
            }
            if (tx == 0) {
                const int row = row0 + ty * 8 + i;
                s_arr[h * N_NODES + row] = ps;
                t_arr[h * N_NODES + row] = pt;
            }
        }
    } else {
        // ---------------- scan path: one adjacency row per block ----------------
        const int r = (blockIdx.y - NHEADS) * gridDim.x + blockIdx.x; // 0..6143
        const int wid = tid >> 6;
        const int lane = tid & 63;
        const unsigned long long lower = (1ull << lane) - 1ull;

        if (tid == 0) sm.s.cnt = 0;
        __syncthreads();
        const int* arow = adj + (size_t)r * N_NODES;
#pragma unroll
        for (int it = 0; it < 6; ++it) {
            const int j0 = it * 1024 + wid * 256 + lane * 4;
            const int4 v = *(const int4*)(arow + j0);
            const unsigned long long b0 = __ballot(v.x != 0);
            const unsigned long long b1 = __ballot(v.y != 0);
            const unsigned long long b2 = __ballot(v.z != 0);
            const unsigned long long b3 = __ballot(v.w != 0);
            const int n0 = __popcll(b0), n1 = __popcll(b1);
            const int n2 = __popcll(b2), n3 = __popcll(b3);
            const int tot = n0 + n1 + n2 + n3;
            int base = 0;
            if (lane == 0 && tot) base = atomicAdd(&sm.s.cnt, tot);
            base = __shfl(base, 0);
            int p;
            if (v.x) { p = base + __popcll(b0 & lower); if (p < MAXC) sm.s.nbr[p] = (unsigned short)j0; }
            base += n0;
            if (v.y) { p = base + __popcll(b1 & lower); if (p < MAXC) sm.s.nbr[p] = (unsigned short)(j0 + 1); }
            base += n1;
            if (v.z) { p = base + __popcll(b2 & lower); if (p < MAXC) sm.s.nbr[p] = (unsigned short)(j0 + 2); }
            base += n2;
            if (v.w) { p = base + __popcll(b3 & lower); if (p < MAXC) sm.s.nbr[p] = (unsigned short)(j0 + 3); }
        }
        __syncthreads();
        const int c = sm.s.cnt;
        const int cc = c < MAXC ? c : MAXC;
        for (int k = tid; k < cc; k += 256)
            nbr_g[(size_t)r * MAXC + k] = sm.s.nbr[k];
        if (tid == 0) cnt_g[r] = c;
    }
}

// ---------------------------------------------------------------------------
// Kernel 2: CSR-consuming attention. Block = dst node i; wave h = head h.
// ---------------------------------------------------------------------------
__global__ __launch_bounds__(256) void attn_agg(const int* __restrict__ adj,
                                                const float* __restrict__ Wh,
                                                const float* __restrict__ s_arr,
                                                const float* __restrict__ t_arr,
                                                const int* __restrict__ cnt_g,
                                                const unsigned short* __restrict__ nbr_g,
                                                float* __restrict__ hcat) {
    __shared__ unsigned short nbr[MAXC];
    __shared__ float p_s[NHEADS][MAXC];
    const int i = blockIdx.x;
    const int tid = threadIdx.x;
    const int h = tid >> 6;
    const int lane = tid & 63;
    const int c = cnt_g[i];
    const float* whp = Wh + (size_t)h * N_NODES * DHEAD;

    float acc, l;
    if (c > 0 && c <= MAXC) {
        for (int k = tid; k < c; k += 256) nbr[k] = nbr_g[(size_t)i * MAXC + k];
        __syncthreads();

        const float s_h = s_arr[h * N_NODES + i];
        const float* tp = t_arr + (size_t)h * N_NODES;
        float m = -INFINITY;
        for (int k = lane; k < c; k += 64) {
            float e = s_h + tp[nbr[k]];
            e = e >= 0.0f ? e : LRELU_ALPHA * e;
            p_s[h][k] = e;
            m = fmaxf(m, e);
        }
#pragma unroll
        for (int off = 32; off > 0; off >>= 1) m = fmaxf(m, __shfl_xor(m, off));
        float ls = 0.0f;
        for (int k = lane; k < c; k += 64) {
            const float p = __expf(p_s[h][k] - m);
            p_s[h][k] = p;
            ls += p;
        }
#pragma unroll
        for (int off = 32; off > 0; off >>= 1) ls += __shfl_xor(ls, off);
        l = ls;
        // p_s[h] is wave-private: no barrier needed.

        float a0 = 0.f, a1 = 0.f, a2 = 0.f, a3 = 0.f;
        float a4 = 0.f, a5 = 0.f, a6 = 0.f, a7 = 0.f;
        int k = 0;
        for (; k + 8 <= c; k += 8) {
            const int j0 = nbr[k],     j1 = nbr[k + 1], j2 = nbr[k + 2], j3 = nbr[k + 3];
            const int j4 = nbr[k + 4], j5 = nbr[k + 5], j6 = nbr[k + 6], j7 = nbr[k + 7];
            const float p0 = p_s[h][k],     p1 = p_s[h][k + 1];
            const float p2 = p_s[h][k + 2], p3 = p_s[h][k + 3];
            const float p4 = p_s[h][k + 4], p5 = p_s[h][k + 5];
            const float p6 = p_s[h][k + 6], p7 = p_s[h][k + 7];
            a0 += p0 * whp[(size_t)j0 * DHEAD + lane];
            a1 += p1 * whp[(size_t)j1 * DHEAD + lane];
            a2 += p2 * whp[(size_t)j2 * DHEAD + lane];
            a3 += p3 * whp[(size_t)j3 * DHEAD + lane];
            a4 += p4 * whp[(size_t)j4 * DHEAD + lane];
            a5 += p5 * whp[(size_t)j5 * DHEAD + lane];
            a6 += p6 * whp[(size_t)j6 * DHEAD + lane];
            a7 += p7 * whp[(size_t)j7 * DHEAD + lane];
        }
        for (; k < c; k++) a0 += p_s[h][k] * whp[(size_t)nbr[k] * DHEAD + lane];
        acc = ((a0 + a1) + (a2 + a3)) + ((a4 + a5) + (a6 + a7));
    } else if (c == 0) {
        acc = 0.0f;
        for (int j = 0; j < N_NODES; j++) acc += whp[(size_t)j * DHEAD + lane];
        l = (float)N_NODES;
    } else {
        // c > MAXC: serial rescan of the adjacency row (never expected at 1%)
        const int* arow = adj + (size_t)i * N_NODES;
        const float s_h = s_arr[h * N_NODES + i];
        const float* tp = t_arr + (size_t)h * N_NODES;
        float m = -INFINITY, ll = 0.0f;
        acc = 0.0f;
        for (int j = 0; j < N_NODES; j++) {
            if (arow[j]) {
                float e = s_h + tp[j];
                e = e >= 0.0f ? e : LRELU_ALPHA * e;
                const float m_new = fmaxf(m, e);
                const float scale = __expf(m - m_new);
                const float p = __expf(e - m_new);
                ll = ll * scale + p;
                acc = acc * scale + p * whp[(size_t)j * DHEAD + lane];
                m = m_new;
            }
        }
        l = ll;
    }
    float hv = acc / l;
    hv = hv > 0.0f ? hv : expm1f(hv);
    hcat[(size_t)i * NHID + h * DHEAD + lane] = hv;
}

// ---------------------------------------------------------------------------
// Kernel 3: out = elu(hcat @ lin_w^T + b)
// ---------------------------------------------------------------------------
__global__ __launch_bounds__(256) void out_gemm(const float* __restrict__ hcat,
                                                const float* __restrict__ lin_w,
                                                const float* __restrict__ lin_b,
                                                float* __restrict__ out) {
    __shared__ float As[64][ASTRIDE * 4];
    __shared__ float Bs[16][64];
    const int tid = threadIdx.x;
    const int tx = tid & 15;
    const int ty = tid >> 4;
    const int row0 = blockIdx.x * 64;
    const int c0 = blockIdx.y * 64;

    float acc[4][4] = {};

    for (int k0 = 0; k0 < NHID; k0 += 16) {
        {
            const int r = tid >> 2, kq = tid & 3;
            const float4 v = *(const float4*)(hcat + (size_t)(row0 + r) * NHID + k0 + kq * 4);
            *(float4*)&As[r][kq * 4] = v;
        }
        {
            const int cc = tid & 63, kq = tid >> 6;
            const float4 v = *(const float4*)(lin_w + (size_t)(c0 + cc) * NHID + k0 + kq * 4);
            Bs[kq * 4 + 0][cc] = v.x;
            Bs[kq * 4 + 1][cc] = v.y;
            Bs[kq * 4 + 2][cc] = v.z;
            Bs[kq * 4 + 3][cc] = v.w;
        }
        __syncthreads();
#pragma unroll
        for (int kk = 0; kk < 16; kk++) {
            float a[4], b[4];
#pragma unroll
            for (int i = 0; i < 4; i++) a[i] = As[ty * 4 + i][kk];
#pragma unroll
            for (int j = 0; j < 4; j++) b[j] = Bs[kk][tx * 4 + j];
#pragma unroll
            for (int i = 0; i < 4; i++)
#pragma unroll
                for (int j = 0; j < 4; j++) acc[i][j] += a[i] * b[j];
        }
        __syncthreads();
    }
#pragma unroll
    for (int i = 0; i < 4; i++) {
        const int row = row0 + ty * 4 + i;
        float v[4];
#pragma unroll
        for (int j = 0; j < 4; j++) {
            const int col = c0 + tx * 4 + j;
            float val = acc[i][j] + lin_b[col];
            v[j] = val > 0.0f ? val : expm1f(val);
        }
        *(float4*)(out + (size_t)row * NEMBED + c0 + tx * 4) =
            make_float4(v[0], v[1], v[2], v[3]);
    }
}

extern "C" void kernel_launch(void* const* d_in, const int* in_sizes, int n_in,
                              void* d_out, int out_size, void* d_ws, size_t ws_size,
                              hipStream_t stream) {
    const float* x     = (const float*)d_in[0];
    const int*   adj   = (const int*)d_in[1];
    const float* W     = (const float*)d_in[2];
    const float* a_src = (const float*)d_in[3];
    const float* a_dst = (const float*)d_in[4];
    const float* lin_w = (const float*)d_in[5];
    const float* lin_b = (const float*)d_in[6];
    float* out = (float*)d_out;

    float* Wh   = (float*)d_ws;                                   // H*N*D floats
    float* s    = Wh + (size_t)NHEADS * N_NODES * DHEAD;
    float* t    = s + (size_t)NHEADS * N_NODES;
    float* hcat = t + (size_t)NHEADS * N_NODES;                   // N*NHID floats
    int* cnt_g  = (int*)(hcat + (size_t)N_NODES * NHID);          // N ints
    unsigned short* nbr_g = (unsigned short*)(cnt_g + N_NODES);   // N*MAXC ushort

    gemm_scan<<<dim3(48, NHEADS + 128), 256, 0, stream>>>(
        x, W, a_src, a_dst, adj, Wh, s, t, cnt_g, nbr_g);
    attn_agg<<<N_NODES, 256, 0, stream>>>(adj, Wh, s, t, cnt_g, nbr_g, hcat);
    out_gemm<<<dim3(N_NODES / 64, NEMBED / 64), 256, 0, stream>>>(hcat, lin_w, lin_b, out);
}

// Round 7
// 286.441 us; speedup vs baseline: 1.0440x; 1.0440x over previous
//
#include <hip/hip_runtime.h>
#include <hip/hip_bf16.h>
#include <math.h>

#define N_NODES 6144
#define NFEAT 512
#define NHID 256
#define NHEADS 4
#define DHEAD 64
#define NEMBED 128
#define LRELU_ALPHA 0.2f
#define MAXC 256          // CSR capacity/row; degree ~Binom(6144,1%): mean 61, max~100
#define ASTRIDE 20        // As row pad: breaks 4-way read conflict, keeps 16B align

// ---------------------------------------------------------------------------
// Kernel 1: grid (96, 68).
//  y<4 : Wh[h]=x.W[h] 64x64-tile fp32 GEMM (R5 shape) + fused s/t epilogue.
//  y>=4: ONE adjacency row per block, LDS-free flat scan: per-lane nonzero
//        count -> one global atomicAdd -> direct ushort stores. No ballots,
//        no barriers; all 6 int4 loads hoistable -> deep VMEM pipeline.
// ---------------------------------------------------------------------------
__global__ __launch_bounds__(256) void gemm_scan(const float* __restrict__ x,
                                                 const float* __restrict__ W,
                                                 const float* __restrict__ a_src,
                                                 const float* __restrict__ a_dst,
                                                 const int* __restrict__ adj,
                                                 float* __restrict__ Wh,
                                                 float* __restrict__ s_arr,
                                                 float* __restrict__ t_arr,
                                                 int* __restrict__ cnt_g,
                                                 unsigned short* __restrict__ nbr_g) {
    __shared__ float As[64][ASTRIDE];
    __shared__ float Bs[16][64];
    const int tid = threadIdx.x;

    if (blockIdx.y < NHEADS) {
        // ---------------- GEMM path ----------------
        const int tx = tid & 15;
        const int ty = tid >> 4;
        const int row0 = blockIdx.x * 64;
        const int h = blockIdx.y;
        const float* Bp = W + (size_t)h * NFEAT * DHEAD;

        float acc[4][4] = {};

        for (int k0 = 0; k0 < NFEAT; k0 += 16) {
            {
                const int r = tid >> 2, kq = tid & 3;
                const float4 v = *(const float4*)(x + (size_t)(row0 + r) * NFEAT + k0 + kq * 4);
                *(float4*)&As[r][kq * 4] = v;
            }
            {
                const int kk = tid >> 4, cq = tid & 15;
                const float4 v = *(const float4*)(Bp + (size_t)(k0 + kk) * DHEAD + cq * 4);
                *(float4*)&Bs[kk][cq * 4] = v;
            }
            __syncthreads();
#pragma unroll
            for (int kk = 0; kk < 16; kk++) {
                float a[4], b[4];
#pragma unroll
                for (int i = 0; i < 4; i++) a[i] = As[ty * 4 + i][kk];
#pragma unroll
                for (int j = 0; j < 4; j++) b[j] = Bs[kk][tx * 4 + j];
#pragma unroll
                for (int i = 0; i < 4; i++)
#pragma unroll
                    for (int j = 0; j < 4; j++) acc[i][j] += a[i] * b[j];
            }
            __syncthreads();
        }
#pragma unroll
        for (int i = 0; i < 4; i++) {
            const int row = row0 + ty * 4 + i;
            float4 v = make_float4(acc[i][0], acc[i][1], acc[i][2], acc[i][3]);
            *(float4*)(Wh + ((size_t)h * N_NODES + row) * DHEAD + tx * 4) = v;
        }
        // fused s/t epilogue
        float a4s[4], a4d[4];
#pragma unroll
        for (int j = 0; j < 4; j++) {
            a4s[j] = a_src[h * DHEAD + tx * 4 + j];
            a4d[j] = a_dst[h * DHEAD + tx * 4 + j];
        }
#pragma unroll
        for (int i = 0; i < 4; i++) {
            float ps = acc[i][0] * a4s[0] + acc[i][1] * a4s[1] +
                       acc[i][2] * a4s[2] + acc[i][3] * a4s[3];
            float pt = acc[i][0] * a4d[0] + acc[i][1] * a4d[1] +
                       acc[i][2] * a4d[2] + acc[i][3] * a4d[3];
#pragma unroll
            for (int off = 1; off < 16; off <<= 1) {
                ps += __shfl_xor(ps, off);
                pt += __shfl_xor(pt, off);
            }
            if (tx == 0) {
                const int row = row0 + ty * 4 + i;
                s_arr[h * N_NODES + row] = ps;
                t_arr[h * N_NODES + row] = pt;
            }
        }
    } else {
        // ---------------- scan path: one row per block, LDS-free ----------------
        const int r = (blockIdx.y - NHEADS) * gridDim.x + blockIdx.x; // 0..6143
        const int* arow = adj + (size_t)r * N_NODES;
        unsigned short* nrow = nbr_g + (size_t)r * MAXC;
        int* cp = cnt_g + r;
#pragma unroll
        for (int it = 0; it < 6; ++it) {
            const int j0 = it * 1024 + tid * 4;
            const int4 v = *(const int4*)(arow + j0);
            const int n = (v.x != 0) + (v.y != 0) + (v.z != 0) + (v.w != 0);
            if (n) {
                int base = atomicAdd(cp, n);
                if (v.x) { if (base < MAXC) nrow[base] = (unsigned short)j0; ++base; }
                if (v.y) { if (base < MAXC) nrow[base] = (unsigned short)(j0 + 1); ++base; }
                if (v.z) { if (base < MAXC) nrow[base] = (unsigned short)(j0 + 2); ++base; }
                if (v.w) { if (base < MAXC) nrow[base] = (unsigned short)(j0 + 3); }
            }
        }
    }
}

// ---------------------------------------------------------------------------
// Kernel 2: CSR-consuming attention. Block = dst node i; wave h = head h.
// ---------------------------------------------------------------------------
__global__ __launch_bounds__(256) void attn_agg(const int* __restrict__ adj,
                                                const float* __restrict__ Wh,
                                                const float* __restrict__ s_arr,
                                                const float* __restrict__ t_arr,
                                                const int* __restrict__ cnt_g,
                                                const unsigned short* __restrict__ nbr_g,
                                                float* __restrict__ hcat) {
    __shared__ unsigned short nbr[MAXC];
    __shared__ float p_s[NHEADS][MAXC];
    const int i = blockIdx.x;
    const int tid = threadIdx.x;
    const int h = tid >> 6;
    const int lane = tid & 63;
    const int c = cnt_g[i];
    const float* whp = Wh + (size_t)h * N_NODES * DHEAD;

    float acc, l;
    if (c > 0 && c <= MAXC) {
        for (int k = tid; k < c; k += 256) nbr[k] = nbr_g[(size_t)i * MAXC + k];
        __syncthreads();

        const float s_h = s_arr[h * N_NODES + i];
        const float* tp = t_arr + (size_t)h * N_NODES;
        float m = -INFINITY;
        for (int k = lane; k < c; k += 64) {
            float e = s_h + tp[nbr[k]];
            e = e >= 0.0f ? e : LRELU_ALPHA * e;
            p_s[h][k] = e;
            m = fmaxf(m, e);
        }
#pragma unroll
        for (int off = 32; off > 0; off >>= 1) m = fmaxf(m, __shfl_xor(m, off));
        float ls = 0.0f;
        for (int k = lane; k < c; k += 64) {
            const float p = __expf(p_s[h][k] - m);
            p_s[h][k] = p;
            ls += p;
        }
#pragma unroll
        for (int off = 32; off > 0; off >>= 1) ls += __shfl_xor(ls, off);
        l = ls;
        // p_s[h] is wave-private: no barrier needed.

        float a0 = 0.f, a1 = 0.f, a2 = 0.f, a3 = 0.f;
        float a4 = 0.f, a5 = 0.f, a6 = 0.f, a7 = 0.f;
        int k = 0;
        for (; k + 8 <= c; k += 8) {
            const int j0 = nbr[k],     j1 = nbr[k + 1], j2 = nbr[k + 2], j3 = nbr[k + 3];
            const int j4 = nbr[k + 4], j5 = nbr[k + 5], j6 = nbr[k + 6], j7 = nbr[k + 7];
            const float p0 = p_s[h][k],     p1 = p_s[h][k + 1];
            const float p2 = p_s[h][k + 2], p3 = p_s[h][k + 3];
            const float p4 = p_s[h][k + 4], p5 = p_s[h][k + 5];
            const float p6 = p_s[h][k + 6], p7 = p_s[h][k + 7];
            a0 += p0 * whp[(size_t)j0 * DHEAD + lane];
            a1 += p1 * whp[(size_t)j1 * DHEAD + lane];
            a2 += p2 * whp[(size_t)j2 * DHEAD + lane];
            a3 += p3 * whp[(size_t)j3 * DHEAD + lane];
            a4 += p4 * whp[(size_t)j4 * DHEAD + lane];
            a5 += p5 * whp[(size_t)j5 * DHEAD + lane];
            a6 += p6 * whp[(size_t)j6 * DHEAD + lane];
            a7 += p7 * whp[(size_t)j7 * DHEAD + lane];
        }
        for (; k < c; k++) a0 += p_s[h][k] * whp[(size_t)nbr[k] * DHEAD + lane];
        acc = ((a0 + a1) + (a2 + a3)) + ((a4 + a5) + (a6 + a7));
    } else if (c == 0) {
        acc = 0.0f;
        for (int j = 0; j < N_NODES; j++) acc += whp[(size_t)j * DHEAD + lane];
        l = (float)N_NODES;
    } else {
        // c > MAXC: serial rescan of the adjacency row (never expected at 1%)
        const int* arow = adj + (size_t)i * N_NODES;
        const float s_h = s_arr[h * N_NODES + i];
        const float* tp = t_arr + (size_t)h * N_NODES;
        float m = -INFINITY, ll = 0.0f;
        acc = 0.0f;
        for (int j = 0; j < N_NODES; j++) {
            if (arow[j]) {
                float e = s_h + tp[j];
                e = e >= 0.0f ? e : LRELU_ALPHA * e;
                const float m_new = fmaxf(m, e);
                const float scale = __expf(m - m_new);
                const float p = __expf(e - m_new);
                ll = ll * scale + p;
                acc = acc * scale + p * whp[(size_t)j * DHEAD + lane];
                m = m_new;
            }
        }
        l = ll;
    }
    float hv = acc / l;
    hv = hv > 0.0f ? hv : expm1f(hv);
    hcat[(size_t)i * NHID + h * DHEAD + lane] = hv;
}

// ---------------------------------------------------------------------------
// Kernel 3: out = elu(hcat @ lin_w^T + b)
// ---------------------------------------------------------------------------
__global__ __launch_bounds__(256) void out_gemm(const float* __restrict__ hcat,
                                                const float* __restrict__ lin_w,
                                                const float* __restrict__ lin_b,
                                                float* __restrict__ out) {
    __shared__ float As[64][ASTRIDE * 4];
    __shared__ float Bs[16][64];
    const int tid = threadIdx.x;
    const int tx = tid & 15;
    const int ty = tid >> 4;
    const int row0 = blockIdx.x * 64;
    const int c0 = blockIdx.y * 64;

    float acc[4][4] = {};

    for (int k0 = 0; k0 < NHID; k0 += 16) {
        {
            const int r = tid >> 2, kq = tid & 3;
            const float4 v = *(const float4*)(hcat + (size_t)(row0 + r) * NHID + k0 + kq * 4);
            *(float4*)&As[r][kq * 4] = v;
        }
        {
            const int cc = tid & 63, kq = tid >> 6;
            const float4 v = *(const float4*)(lin_w + (size_t)(c0 + cc) * NHID + k0 + kq * 4);
            Bs[kq * 4 + 0][cc] = v.x;
            Bs[kq * 4 + 1][cc] = v.y;
            Bs[kq * 4 + 2][cc] = v.z;
            Bs[kq * 4 + 3][cc] = v.w;
        }
        __syncthreads();
#pragma unroll
        for (int kk = 0; kk < 16; kk++) {
            float a[4], b[4];
#pragma unroll
            for (int i = 0; i < 4; i++) a[i] = As[ty * 4 + i][kk];
#pragma unroll
            for (int j = 0; j < 4; j++) b[j] = Bs[kk][tx * 4 + j];
#pragma unroll
            for (int i = 0; i < 4; i++)
#pragma unroll
                for (int j = 0; j < 4; j++) acc[i][j] += a[i] * b[j];
        }
        __syncthreads();
    }
#pragma unroll
    for (int i = 0; i < 4; i++) {
        const int row = row0 + ty * 4 + i;
        float v[4];
#pragma unroll
        for (int j = 0; j < 4; j++) {
            const int col = c0 + tx * 4 + j;
            float val = acc[i][j] + lin_b[col];
            v[j] = val > 0.0f ? val : expm1f(val);
        }
        *(float4*)(out + (size_t)row * NEMBED + c0 + tx * 4) =
            make_float4(v[0], v[1], v[2], v[3]);
    }
}

extern "C" void kernel_launch(void* const* d_in, const int* in_sizes, int n_in,
                              void* d_out, int out_size, void* d_ws, size_t ws_size,
                              hipStream_t stream) {
    const float* x     = (const float*)d_in[0];
    const int*   adj   = (const int*)d_in[1];
    const float* W     = (const float*)d_in[2];
    const float* a_src = (const float*)d_in[3];
    const float* a_dst = (const float*)d_in[4];
    const float* lin_w = (const float*)d_in[5];
    const float* lin_b = (const float*)d_in[6];
    float* out = (float*)d_out;

    float* Wh   = (float*)d_ws;                                   // H*N*D floats
    float* s    = Wh + (size_t)NHEADS * N_NODES * DHEAD;
    float* t    = s + (size_t)NHEADS * N_NODES;
    float* hcat = t + (size_t)NHEADS * N_NODES;                   // N*NHID floats
    int* cnt_g  = (int*)(hcat + (size_t)N_NODES * NHID);          // N ints
    unsigned short* nbr_g = (unsigned short*)(cnt_g + N_NODES);   // N*MAXC ushort

    hipMemsetAsync(cnt_g, 0, N_NODES * sizeof(int), stream);
    gemm_scan<<<dim3(96, NHEADS + 64), 256, 0, stream>>>(
        x, W, a_src, a_dst, adj, Wh, s, t, cnt_g, nbr_g);
    attn_agg<<<N_NODES, 256, 0, stream>>>(adj, Wh, s, t, cnt_g, nbr_g, hcat);
    out_gemm<<<dim3(N_NODES / 64, NEMBED / 64), 256, 0, stream>>>(hcat, lin_w, lin_b, out);
}